// Round 5
// baseline (816.830 us; speedup 1.0000x reference)
//
#include <hip/hip_runtime.h>
#include <stdint.h>

// Problem constants (match reference)
#define S_TOK 16384
#define MDIM  1024
#define NEXP  64
#define CAP   256   // ceil(S/E * 1.0), >= MIN_CAPACITY

static constexpr size_t SEC    = (size_t)S_TOK * NEXP * CAP;  // 268435456
static constexpr size_t CW_OFF = 1;                            // combine_weights
static constexpr size_t EC_OFF = 1 + 2 * SEC;                  // exp_counts (as float)
static constexpr size_t AL_OFF = EC_OFF + NEXP;                // alpha

// Zero-fill geometry: floats [1, 1+2*SEC). Scalars 1,2,3 and 2*SEC; float4 quads
// over [4, 4 + 4*NQ4). NQ4 = 134217727. 2048 fill blocks x 65536 quads.
static constexpr size_t NQ4    = 134217727;
static constexpr int    NFILLB = 2048;
static constexpr size_t QPB    = 65536;      // quads per fill block

// ---------------- Threefry-2x32-20 == jax.random.uniform(key(42), (S,E)) ----------------
__device__ __forceinline__ uint32_t rotl32(uint32_t x, int n) {
  return (x << n) | (x >> (32 - n));
}

__device__ float jax_u01(uint32_t i) {
  const uint32_t half = (uint32_t)(S_TOK * NEXP / 2);  // 524288
  uint32_t x0, x1;
  const bool hi = (i >= half);
  if (hi) { x0 = i - half; x1 = i; } else { x0 = i; x1 = i + half; }
  const uint32_t ks0 = 0u;
  const uint32_t ks1 = 42u;
  const uint32_t ks2 = 0x1BD11BDAu ^ ks0 ^ ks1;
  x0 += ks0; x1 += ks1;
#define TF_R(r) { x0 += x1; x1 = rotl32(x1, (r)); x1 ^= x0; }
  TF_R(13) TF_R(15) TF_R(26) TF_R(6)
  x0 += ks1; x1 += ks2 + 1u;
  TF_R(17) TF_R(29) TF_R(16) TF_R(24)
  x0 += ks2; x1 += ks0 + 2u;
  TF_R(13) TF_R(15) TF_R(26) TF_R(6)
  x0 += ks0; x1 += ks1 + 3u;
  TF_R(17) TF_R(29) TF_R(16) TF_R(24)
  x0 += ks1; x1 += ks2 + 4u;
  TF_R(13) TF_R(15) TF_R(26) TF_R(6)
  x0 += ks2; x1 += ks0 + 5u;
#undef TF_R
  const uint32_t bits = hi ? x1 : x0;
  return __uint_as_float((bits >> 9) | 0x3F800000u) - 1.0f;  // [0,1)
}

// ---------------- K1: gate GEMM (fp32, reg-prefetch double-buffer) + softmax ----------------
// 256 blocks x 256 threads, 64 tokens/block, 4x4 register tile.
__global__ __launch_bounds__(256) void k_gate(
    const float* __restrict__ x, const float* __restrict__ wg,
    float* __restrict__ out,
    int* __restrict__ expert_ws, float* __restrict__ uval_ws,
    float* __restrict__ alpha_ws, float* __restrict__ colsum_ws)
{
  __shared__ float xs[64][68];   // GEMM x-tile; later reused for logits (swizzled cols)
  __shared__ float wsh[64][68];  // w-tile, XOR-swizzled float4 slots
  __shared__ float sm_m[64], sm_inv[64];

  const int tid  = threadIdx.x;
  const int tok0 = blockIdx.x * 64;
  const int tr   = tid >> 4;   // token group 0..15
  const int tc   = tid & 15;   // expert group 0..15
  const int lr   = tid >> 4;   // staging row base 0..15
  const int lf   = tid & 15;   // staging float4 col 0..15

  float acc[4][4] = {};
  float4 xr[4], wr[4];

  // prefetch chunk 0
#pragma unroll
  for (int i = 0; i < 4; ++i) {
    const int r = lr + 16 * i;
    xr[i] = *(const float4*)(x  + (size_t)(tok0 + r) * MDIM + lf * 4);
    wr[i] = *(const float4*)(wg + (size_t)r * MDIM + lf * 4);
  }

  for (int t = 0; t < 16; ++t) {
    __syncthreads();   // previous chunk's compute done
#pragma unroll
    for (int i = 0; i < 4; ++i) {
      const int r = lr + 16 * i;
      *(float4*)(&xs[r][lf * 4]) = xr[i];
      const int fs = lf ^ ((r >> 2) & 7);
      *(float4*)(&wsh[r][fs * 4]) = wr[i];
    }
    if (t < 15) {      // issue next-chunk loads; latency hides under compute below
      const int kc = (t + 1) * 64;
#pragma unroll
      for (int i = 0; i < 4; ++i) {
        const int r = lr + 16 * i;
        xr[i] = *(const float4*)(x  + (size_t)(tok0 + r) * MDIM + kc + lf * 4);
        wr[i] = *(const float4*)(wg + (size_t)r * MDIM + kc + lf * 4);
      }
    }
    __syncthreads();   // LDS tile visible
#pragma unroll
    for (int k4 = 0; k4 < 16; ++k4) {
      float4 a[4], b[4];
#pragma unroll
      for (int i = 0; i < 4; ++i)
        a[i] = *(const float4*)(&xs[tr * 4 + i][k4 * 4]);
#pragma unroll
      for (int j = 0; j < 4; ++j) {
        const int e  = tc * 4 + j;
        const int fs = k4 ^ ((e >> 2) & 7);
        b[j] = *(const float4*)(&wsh[e][fs * 4]);
      }
#pragma unroll
      for (int i = 0; i < 4; ++i)
#pragma unroll
        for (int j = 0; j < 4; ++j)
          acc[i][j] += a[i].x * b[j].x + a[i].y * b[j].y +
                       a[i].z * b[j].z + a[i].w * b[j].w;
    }
  }

  // Dump logits to LDS with +r column swizzle (breaks stride-68 bank conflicts)
  __syncthreads();
#pragma unroll
  for (int i = 0; i < 4; ++i)
#pragma unroll
    for (int j = 0; j < 4; ++j) {
      const int r = tr * 4 + i, c = tc * 4 + j;
      xs[r][(c + r) & 63] = acc[i][j];
    }
  __syncthreads();

  // Pass 1: max/argmax + exp-sum per token (threads 0..63; 2-way bank aliasing = free)
  if (tid < 64) {
    const int t = tid;
    float mx = -3.0e38f; int am = 0;
    for (int e = 0; e < NEXP; ++e) {
      const float v = xs[t][(e + t) & 63];
      if (v > mx) { mx = v; am = e; }   // strict '>' == jnp.argmax first-max
    }
    float sum = 0.f;
    for (int e = 0; e < NEXP; ++e) sum += expf(xs[t][(e + t) & 63] - mx);
    const float inv = 1.0f / sum;        // gate at argmax == alpha
    sm_m[t] = mx; sm_inv[t] = inv;

    const int s = tok0 + t;
    expert_ws[s] = am;
    alpha_ws[s]  = inv;
    out[AL_OFF + s] = inv;
    uval_ws[s] = jax_u01((uint32_t)s * (uint32_t)NEXP + (uint32_t)am);
  }
  __syncthreads();

  // Pass 2: per-expert column sums of normalized gates (thread e; stride-1 reads)
  if (tid < 64) {
    const int e = tid;
    float s = 0.f;
    for (int t = 0; t < 64; ++t)
      s += expf(xs[t][(e + t) & 63] - sm_m[t]) * sm_inv[t];
    colsum_ws[(size_t)blockIdx.x * 64 + e] = s;
  }
}

// ---------------- K2: fused {select (blocks 0..63)} + {2.15 GB zero-fill} ----------------
// Select: ~130 KB L2 reads + 12 KB LDS — hides under the fill. Fill blocks:
// persistent grid-stride, no LDS pressure on occupancy, plain float4 stores
// (fillBufferAligned pattern, measured 6.43 TB/s).
__global__ __launch_bounds__(256) void k_select_fill(
    const int* __restrict__ expert_ws, const float* __restrict__ uval_ws,
    int* __restrict__ slotj_ws, int* __restrict__ counts_ws,
    float* __restrict__ out)
{
  __shared__ float su[1024];
  __shared__ int   sidx[1024];
  __shared__ int   skept[1024];
  __shared__ int   scnt;

  const int tid = threadIdx.x;

  if (blockIdx.x >= 64) {
    // ---- fill path ----
    const int fb = blockIdx.x - 64;
    const size_t qend = min(((size_t)fb + 1) * QPB, NQ4);
    const float4 z = make_float4(0.f, 0.f, 0.f, 0.f);
    float* const p4 = out + 4;   // 16B-aligned quad base
    for (size_t q = (size_t)fb * QPB + tid; q < qend; q += 256)
      *(float4*)(p4 + q * 4) = z;
    if (fb == 0) {
      if (tid < 3)       out[1 + tid]     = 0.f;   // floats 1,2,3
      else if (tid == 3) out[2 * SEC]     = 0.f;   // last float of region
    }
    return;
  }

  // ---- select path (blocks 0..63, one expert each) ----
  const int e = blockIdx.x;
  if (tid == 0) scnt = 0;
  __syncthreads();

  for (int s = tid; s < S_TOK; s += 256) {
    if (expert_ws[s] == e) {
      const int p = atomicAdd(&scnt, 1);
      if (p < 1024) { su[p] = uval_ws[s]; sidx[p] = s; }  // n ~ 256±16; huge headroom
    }
  }
  __syncthreads();
  const int n = min(scnt, 1024);

  if (tid == 0) {
    counts_ws[e] = scnt;
    out[EC_OFF + e] = (float)scnt;   // exp_counts (pre-capacity)
  }

  for (int t = tid; t < n; t += 256) {
    int keep = 1;
    if (n > CAP) {
      const float ut = su[t];
      const int   it = sidx[t];
      int r = 0;
      for (int j = 0; j < n; ++j) {
        const float uj = su[j];
        r += (uj > ut) || (uj == ut && sidx[j] < it);
      }
      keep = (r < CAP);
    }
    skept[t] = keep;
  }
  __syncthreads();

  for (int t = tid; t < n; t += 256) {
    const int it = sidx[t];
    int sj = -1;
    if (skept[t]) {
      int slot = 0;
      for (int j = 0; j < n; ++j) slot += (skept[j] && (sidx[j] < it));
      sj = e * CAP + slot;
    }
    slotj_ws[it] = sj;
  }
}

// ---------------- K3: sparse scatter + l_aux (after fill in stream order) ----------------
__global__ __launch_bounds__(256) void k_scatter_final(
    const int* __restrict__ slotj_ws, const float* __restrict__ alpha_ws,
    const float* __restrict__ colsum_ws, const int* __restrict__ counts_ws,
    float* __restrict__ out)
{
  const int s = blockIdx.x * 256 + threadIdx.x;   // 64 blocks x 256 = 16384 tokens
  const int tj = slotj_ws[s];
  if (tj >= 0) {
    const size_t base = CW_OFF + (size_t)s * (NEXP * CAP) + (size_t)tj;
    out[base]       = alpha_ws[s];   // combine_weights
    out[base + SEC] = 1.0f;          // dispatch_mask
  }

  if (blockIdx.x == 0 && threadIdx.x < 64) {
    const int e = threadIdx.x;
    float cs = 0.f;
    for (int b = 0; b < 256; ++b) cs += colsum_ws[(size_t)b * 64 + e];  // fixed order
    const float me = cs / (float)S_TOK;
    const float ce = (float)counts_ws[e] / (float)S_TOK;
    float v = me * ce;
#pragma unroll
    for (int off = 32; off > 0; off >>= 1) v += __shfl_down(v, off, 64);
    if (e == 0) out[0] = v * (float)NEXP;
  }
}

// ---------------- launch ----------------
extern "C" void kernel_launch(void* const* d_in, const int* in_sizes, int n_in,
                              void* d_out, int out_size, void* d_ws, size_t ws_size,
                              hipStream_t stream)
{
  const float* x  = (const float*)d_in[0];
  const float* wg = (const float*)d_in[1];
  float* out = (float*)d_out;

  // workspace layout
  char* ws = (char*)d_ws;
  int*   expert_ws = (int*)  (ws + 0);        // S ints
  float* uval_ws   = (float*)(ws + 65536);    // S floats
  float* alpha_ws  = (float*)(ws + 131072);   // S floats
  float* colsum_ws = (float*)(ws + 196608);   // 256*64 floats
  int*   counts_ws = (int*)  (ws + 262144);   // 64 ints
  int*   slotj_ws  = (int*)  (ws + 262400);   // S ints

  k_gate         <<<256,         256, 0, stream>>>(x, wg, out, expert_ws, uval_ws,
                                                   alpha_ws, colsum_ws);
  k_select_fill  <<<64 + NFILLB, 256, 0, stream>>>(expert_ws, uval_ws, slotj_ws,
                                                   counts_ws, out);
  k_scatter_final<<<S_TOK / 256, 256, 0, stream>>>(slotj_ws, alpha_ws, colsum_ws,
                                                   counts_ws, out);
}

// Round 6
// 800.320 us; speedup vs baseline: 1.0206x; 1.0206x over previous
//
#include <hip/hip_runtime.h>
#include <stdint.h>

// Problem constants (match reference)
#define S_TOK 16384
#define MDIM  1024
#define NEXP  64
#define CAP   256   // ceil(S/E * 1.0), >= MIN_CAPACITY

static constexpr size_t SEC    = (size_t)S_TOK * NEXP * CAP;  // 268435456
static constexpr size_t CW_OFF = 1;                            // combine_weights
static constexpr size_t EC_OFF = 1 + 2 * SEC;                  // exp_counts (as float)
static constexpr size_t AL_OFF = EC_OFF + NEXP;                // alpha

// Zero-fill geometry: floats [1, 1+2*SEC). Scalars at idx 1,2,3 and 2*SEC;
// float4 quads over [4, 4 + 4*NQ4), NQ4 = 134217727.
// Fill is GLOBAL-STRIDE (fillBufferAligned pattern): thread gid writes quads
// gid, gid+G, gid+2G, ... with G = NFILLB*256 = 524288 -> one 8 MB window
// sweeping forward across the whole GPU (HBM row-buffer friendly).
static constexpr size_t NQ4    = 134217727;
static constexpr int    NFILLB = 2048;
static constexpr size_t GSTR   = (size_t)NFILLB * 256;   // 524288

// ---------------- Threefry-2x32-20 == jax.random.uniform(key(42), (S,E)) ----------------
__device__ __forceinline__ uint32_t rotl32(uint32_t x, int n) {
  return (x << n) | (x >> (32 - n));
}

__device__ float jax_u01(uint32_t i) {
  const uint32_t half = (uint32_t)(S_TOK * NEXP / 2);  // 524288
  uint32_t x0, x1;
  const bool hi = (i >= half);
  if (hi) { x0 = i - half; x1 = i; } else { x0 = i; x1 = i + half; }
  const uint32_t ks0 = 0u;
  const uint32_t ks1 = 42u;
  const uint32_t ks2 = 0x1BD11BDAu ^ ks0 ^ ks1;
  x0 += ks0; x1 += ks1;
#define TF_R(r) { x0 += x1; x1 = rotl32(x1, (r)); x1 ^= x0; }
  TF_R(13) TF_R(15) TF_R(26) TF_R(6)
  x0 += ks1; x1 += ks2 + 1u;
  TF_R(17) TF_R(29) TF_R(16) TF_R(24)
  x0 += ks2; x1 += ks0 + 2u;
  TF_R(13) TF_R(15) TF_R(26) TF_R(6)
  x0 += ks0; x1 += ks1 + 3u;
  TF_R(17) TF_R(29) TF_R(16) TF_R(24)
  x0 += ks1; x1 += ks2 + 4u;
  TF_R(13) TF_R(15) TF_R(26) TF_R(6)
  x0 += ks2; x1 += ks0 + 5u;
#undef TF_R
  const uint32_t bits = hi ? x1 : x0;
  return __uint_as_float((bits >> 9) | 0x3F800000u) - 1.0f;  // [0,1)
}

// ---------------- K1: gate GEMM (fp32, reg-prefetch double-buffer) + softmax ----------------
// 256 blocks x 256 threads, 64 tokens/block, 4x4 register tile.
__global__ __launch_bounds__(256) void k_gate(
    const float* __restrict__ x, const float* __restrict__ wg,
    float* __restrict__ out,
    int* __restrict__ expert_ws, float* __restrict__ uval_ws,
    float* __restrict__ alpha_ws, float* __restrict__ colsum_ws)
{
  __shared__ float xs[64][68];   // GEMM x-tile; later reused for logits (swizzled cols)
  __shared__ float wsh[64][68];  // w-tile, XOR-swizzled float4 slots
  __shared__ float sm_m[64], sm_inv[64];

  const int tid  = threadIdx.x;
  const int tok0 = blockIdx.x * 64;
  const int tr   = tid >> 4;   // token group 0..15
  const int tc   = tid & 15;   // expert group 0..15
  const int lr   = tid >> 4;   // staging row base 0..15
  const int lf   = tid & 15;   // staging float4 col 0..15

  float acc[4][4] = {};
  float4 xr[4], wr[4];

  // prefetch chunk 0
#pragma unroll
  for (int i = 0; i < 4; ++i) {
    const int r = lr + 16 * i;
    xr[i] = *(const float4*)(x  + (size_t)(tok0 + r) * MDIM + lf * 4);
    wr[i] = *(const float4*)(wg + (size_t)r * MDIM + lf * 4);
  }

  for (int t = 0; t < 16; ++t) {
    __syncthreads();   // previous chunk's compute done
#pragma unroll
    for (int i = 0; i < 4; ++i) {
      const int r = lr + 16 * i;
      *(float4*)(&xs[r][lf * 4]) = xr[i];
      const int fs = lf ^ ((r >> 2) & 7);
      *(float4*)(&wsh[r][fs * 4]) = wr[i];
    }
    if (t < 15) {      // issue next-chunk loads; latency hides under compute below
      const int kc = (t + 1) * 64;
#pragma unroll
      for (int i = 0; i < 4; ++i) {
        const int r = lr + 16 * i;
        xr[i] = *(const float4*)(x  + (size_t)(tok0 + r) * MDIM + kc + lf * 4);
        wr[i] = *(const float4*)(wg + (size_t)r * MDIM + kc + lf * 4);
      }
    }
    __syncthreads();   // LDS tile visible
#pragma unroll
    for (int k4 = 0; k4 < 16; ++k4) {
      float4 a[4], b[4];
#pragma unroll
      for (int i = 0; i < 4; ++i)
        a[i] = *(const float4*)(&xs[tr * 4 + i][k4 * 4]);
#pragma unroll
      for (int j = 0; j < 4; ++j) {
        const int e  = tc * 4 + j;
        const int fs = k4 ^ ((e >> 2) & 7);
        b[j] = *(const float4*)(&wsh[e][fs * 4]);
      }
#pragma unroll
      for (int i = 0; i < 4; ++i)
#pragma unroll
        for (int j = 0; j < 4; ++j)
          acc[i][j] += a[i].x * b[j].x + a[i].y * b[j].y +
                       a[i].z * b[j].z + a[i].w * b[j].w;
    }
  }

  // Dump logits to LDS with +r column swizzle (breaks stride-68 bank conflicts)
  __syncthreads();
#pragma unroll
  for (int i = 0; i < 4; ++i)
#pragma unroll
    for (int j = 0; j < 4; ++j) {
      const int r = tr * 4 + i, c = tc * 4 + j;
      xs[r][(c + r) & 63] = acc[i][j];
    }
  __syncthreads();

  // Pass 1: max/argmax + exp-sum per token (threads 0..63)
  if (tid < 64) {
    const int t = tid;
    float mx = -3.0e38f; int am = 0;
    for (int e = 0; e < NEXP; ++e) {
      const float v = xs[t][(e + t) & 63];
      if (v > mx) { mx = v; am = e; }   // strict '>' == jnp.argmax first-max
    }
    float sum = 0.f;
    for (int e = 0; e < NEXP; ++e) sum += expf(xs[t][(e + t) & 63] - mx);
    const float inv = 1.0f / sum;        // gate at argmax == alpha
    sm_m[t] = mx; sm_inv[t] = inv;

    const int s = tok0 + t;
    expert_ws[s] = am;
    alpha_ws[s]  = inv;
    out[AL_OFF + s] = inv;
    uval_ws[s] = jax_u01((uint32_t)s * (uint32_t)NEXP + (uint32_t)am);
  }
  __syncthreads();

  // Pass 2: per-expert column sums of normalized gates (thread e)
  if (tid < 64) {
    const int e = tid;
    float s = 0.f;
    for (int t = 0; t < 64; ++t)
      s += expf(xs[t][(e + t) & 63] - sm_m[t]) * sm_inv[t];
    colsum_ws[(size_t)blockIdx.x * 64 + e] = s;
  }
}

// ---------------- K2: fused {select (blocks 0..63)} + {2.15 GB global-stride fill} ------
__global__ __launch_bounds__(256) void k_select_fill(
    const int* __restrict__ expert_ws, const float* __restrict__ uval_ws,
    int* __restrict__ slotj_ws, int* __restrict__ counts_ws,
    float* __restrict__ out)
{
  __shared__ float su[1024];
  __shared__ int   sidx[1024];
  __shared__ int   skept[1024];
  __shared__ int   scnt;

  const int tid = threadIdx.x;

  if (blockIdx.x >= 64) {
    // ---- fill path: global-stride sweep, fillBufferAligned-identical ----
    const int fb = blockIdx.x - 64;
    const size_t gid = (size_t)fb * 256 + tid;
    const float4 z = make_float4(0.f, 0.f, 0.f, 0.f);
    float* const p4 = out + 4;   // 16B-aligned quad base
    for (size_t q = gid; q < NQ4; q += GSTR)
      *(float4*)(p4 + q * 4) = z;
    if (fb == 0) {
      if (tid < 3)       out[1 + tid] = 0.f;   // floats 1,2,3
      else if (tid == 3) out[2 * SEC] = 0.f;   // last float of zero region
    }
    return;
  }

  // ---- select path (blocks 0..63, one expert each) ----
  const int e = blockIdx.x;
  if (tid == 0) scnt = 0;
  __syncthreads();

  for (int s = tid; s < S_TOK; s += 256) {
    if (expert_ws[s] == e) {
      const int p = atomicAdd(&scnt, 1);
      if (p < 1024) { su[p] = uval_ws[s]; sidx[p] = s; }  // n ~ 256±16; huge headroom
    }
  }
  __syncthreads();
  const int n = min(scnt, 1024);

  if (tid == 0) {
    counts_ws[e] = scnt;
    out[EC_OFF + e] = (float)scnt;   // exp_counts (pre-capacity)
  }

  for (int t = tid; t < n; t += 256) {
    int keep = 1;
    if (n > CAP) {
      const float ut = su[t];
      const int   it = sidx[t];
      int r = 0;
      for (int j = 0; j < n; ++j) {
        const float uj = su[j];
        r += (uj > ut) || (uj == ut && sidx[j] < it);
      }
      keep = (r < CAP);
    }
    skept[t] = keep;
  }
  __syncthreads();

  for (int t = tid; t < n; t += 256) {
    const int it = sidx[t];
    int sj = -1;
    if (skept[t]) {
      int slot = 0;
      for (int j = 0; j < n; ++j) slot += (skept[j] && (sidx[j] < it));
      sj = e * CAP + slot;
    }
    slotj_ws[it] = sj;
  }
}

// ---------------- K3: sparse scatter + l_aux (after fill in stream order) ----------------
__global__ __launch_bounds__(256) void k_scatter_final(
    const int* __restrict__ slotj_ws, const float* __restrict__ alpha_ws,
    const float* __restrict__ colsum_ws, const int* __restrict__ counts_ws,
    float* __restrict__ out)
{
  const int s = blockIdx.x * 256 + threadIdx.x;   // 64 blocks x 256 = 16384 tokens
  const int tj = slotj_ws[s];
  if (tj >= 0) {
    const size_t base = CW_OFF + (size_t)s * (NEXP * CAP) + (size_t)tj;
    out[base]       = alpha_ws[s];   // combine_weights
    out[base + SEC] = 1.0f;          // dispatch_mask
  }

  if (blockIdx.x == 0 && threadIdx.x < 64) {
    const int e = threadIdx.x;
    float cs = 0.f;
    for (int b = 0; b < 256; ++b) cs += colsum_ws[(size_t)b * 64 + e];  // fixed order
    const float me = cs / (float)S_TOK;
    const float ce = (float)counts_ws[e] / (float)S_TOK;
    float v = me * ce;
#pragma unroll
    for (int off = 32; off > 0; off >>= 1) v += __shfl_down(v, off, 64);
    if (e == 0) out[0] = v * (float)NEXP;
  }
}

// ---------------- launch ----------------
extern "C" void kernel_launch(void* const* d_in, const int* in_sizes, int n_in,
                              void* d_out, int out_size, void* d_ws, size_t ws_size,
                              hipStream_t stream)
{
  const float* x  = (const float*)d_in[0];
  const float* wg = (const float*)d_in[1];
  float* out = (float*)d_out;

  // workspace layout
  char* ws = (char*)d_ws;
  int*   expert_ws = (int*)  (ws + 0);        // S ints
  float* uval_ws   = (float*)(ws + 65536);    // S floats
  float* alpha_ws  = (float*)(ws + 131072);   // S floats
  float* colsum_ws = (float*)(ws + 196608);   // 256*64 floats
  int*   counts_ws = (int*)  (ws + 262144);   // 64 ints
  int*   slotj_ws  = (int*)  (ws + 262400);   // S ints

  k_gate         <<<256,         256, 0, stream>>>(x, wg, out, expert_ws, uval_ws,
                                                   alpha_ws, colsum_ws);
  k_select_fill  <<<64 + NFILLB, 256, 0, stream>>>(expert_ws, uval_ws, slotj_ws,
                                                   counts_ws, out);
  k_scatter_final<<<S_TOK / 256, 256, 0, stream>>>(slotj_ws, alpha_ws, colsum_ws,
                                                   counts_ws, out);
}

// Round 7
// 503.393 us; speedup vs baseline: 1.6226x; 1.5899x over previous
//
#include <hip/hip_runtime.h>
#include <stdint.h>

// Problem constants (match reference)
#define S_TOK 16384
#define MDIM  1024
#define NEXP  64
#define CAP   256   // ceil(S/E * 1.0), >= MIN_CAPACITY

static constexpr size_t SEC    = (size_t)S_TOK * NEXP * CAP;  // 268435456
static constexpr size_t CW_OFF = 1;                            // combine_weights
static constexpr size_t EC_OFF = 1 + 2 * SEC;                  // exp_counts (as float)
static constexpr size_t AL_OFF = EC_OFF + NEXP;                // alpha

// ---------------- Threefry-2x32-20 == jax.random.uniform(key(42), (S,E)) ----------------
__device__ __forceinline__ uint32_t rotl32(uint32_t x, int n) {
  return (x << n) | (x >> (32 - n));
}

__device__ float jax_u01(uint32_t i) {
  const uint32_t half = (uint32_t)(S_TOK * NEXP / 2);  // 524288
  uint32_t x0, x1;
  const bool hi = (i >= half);
  if (hi) { x0 = i - half; x1 = i; } else { x0 = i; x1 = i + half; }
  const uint32_t ks0 = 0u;
  const uint32_t ks1 = 42u;
  const uint32_t ks2 = 0x1BD11BDAu ^ ks0 ^ ks1;
  x0 += ks0; x1 += ks1;
#define TF_R(r) { x0 += x1; x1 = rotl32(x1, (r)); x1 ^= x0; }
  TF_R(13) TF_R(15) TF_R(26) TF_R(6)
  x0 += ks1; x1 += ks2 + 1u;
  TF_R(17) TF_R(29) TF_R(16) TF_R(24)
  x0 += ks2; x1 += ks0 + 2u;
  TF_R(13) TF_R(15) TF_R(26) TF_R(6)
  x0 += ks0; x1 += ks1 + 3u;
  TF_R(17) TF_R(29) TF_R(16) TF_R(24)
  x0 += ks1; x1 += ks2 + 4u;
  TF_R(13) TF_R(15) TF_R(26) TF_R(6)
  x0 += ks2; x1 += ks0 + 5u;
#undef TF_R
  const uint32_t bits = hi ? x1 : x0;
  return __uint_as_float((bits >> 9) | 0x3F800000u) - 1.0f;  // [0,1)
}

// ---------------- K1: gate GEMM (fp32, reg-prefetch double-buffer) + softmax ----------------
// 256 blocks x 256 threads, 64 tokens/block, 4x4 register tile.
__global__ __launch_bounds__(256) void k_gate(
    const float* __restrict__ x, const float* __restrict__ wg,
    float* __restrict__ out,
    int* __restrict__ expert_ws, float* __restrict__ uval_ws,
    float* __restrict__ alpha_ws, float* __restrict__ colsum_ws)
{
  __shared__ float xs[64][68];   // GEMM x-tile; later reused for logits (swizzled cols)
  __shared__ float wsh[64][68];  // w-tile, XOR-swizzled float4 slots
  __shared__ float sm_m[64], sm_inv[64];

  const int tid  = threadIdx.x;
  const int tok0 = blockIdx.x * 64;
  const int tr   = tid >> 4;   // token group 0..15
  const int tc   = tid & 15;   // expert group 0..15
  const int lr   = tid >> 4;   // staging row base 0..15
  const int lf   = tid & 15;   // staging float4 col 0..15

  float acc[4][4] = {};
  float4 xr[4], wr[4];

  // prefetch chunk 0
#pragma unroll
  for (int i = 0; i < 4; ++i) {
    const int r = lr + 16 * i;
    xr[i] = *(const float4*)(x  + (size_t)(tok0 + r) * MDIM + lf * 4);
    wr[i] = *(const float4*)(wg + (size_t)r * MDIM + lf * 4);
  }

  for (int t = 0; t < 16; ++t) {
    __syncthreads();   // previous chunk's compute done
#pragma unroll
    for (int i = 0; i < 4; ++i) {
      const int r = lr + 16 * i;
      *(float4*)(&xs[r][lf * 4]) = xr[i];
      const int fs = lf ^ ((r >> 2) & 7);
      *(float4*)(&wsh[r][fs * 4]) = wr[i];
    }
    if (t < 15) {      // issue next-chunk loads; latency hides under compute below
      const int kc = (t + 1) * 64;
#pragma unroll
      for (int i = 0; i < 4; ++i) {
        const int r = lr + 16 * i;
        xr[i] = *(const float4*)(x  + (size_t)(tok0 + r) * MDIM + kc + lf * 4);
        wr[i] = *(const float4*)(wg + (size_t)r * MDIM + kc + lf * 4);
      }
    }
    __syncthreads();   // LDS tile visible
#pragma unroll
    for (int k4 = 0; k4 < 16; ++k4) {
      float4 a[4], b[4];
#pragma unroll
      for (int i = 0; i < 4; ++i)
        a[i] = *(const float4*)(&xs[tr * 4 + i][k4 * 4]);
#pragma unroll
      for (int j = 0; j < 4; ++j) {
        const int e  = tc * 4 + j;
        const int fs = k4 ^ ((e >> 2) & 7);
        b[j] = *(const float4*)(&wsh[e][fs * 4]);
      }
#pragma unroll
      for (int i = 0; i < 4; ++i)
#pragma unroll
        for (int j = 0; j < 4; ++j)
          acc[i][j] += a[i].x * b[j].x + a[i].y * b[j].y +
                       a[i].z * b[j].z + a[i].w * b[j].w;
    }
  }

  // Dump logits to LDS with +r column swizzle (breaks stride-68 bank conflicts)
  __syncthreads();
#pragma unroll
  for (int i = 0; i < 4; ++i)
#pragma unroll
    for (int j = 0; j < 4; ++j) {
      const int r = tr * 4 + i, c = tc * 4 + j;
      xs[r][(c + r) & 63] = acc[i][j];
    }
  __syncthreads();

  // Pass 1: max/argmax + exp-sum per token (threads 0..63)
  if (tid < 64) {
    const int t = tid;
    float mx = -3.0e38f; int am = 0;
    for (int e = 0; e < NEXP; ++e) {
      const float v = xs[t][(e + t) & 63];
      if (v > mx) { mx = v; am = e; }   // strict '>' == jnp.argmax first-max
    }
    float sum = 0.f;
    for (int e = 0; e < NEXP; ++e) sum += expf(xs[t][(e + t) & 63] - mx);
    const float inv = 1.0f / sum;        // gate at argmax == alpha
    sm_m[t] = mx; sm_inv[t] = inv;

    const int s = tok0 + t;
    expert_ws[s] = am;
    alpha_ws[s]  = inv;
    out[AL_OFF + s] = inv;
    uval_ws[s] = jax_u01((uint32_t)s * (uint32_t)NEXP + (uint32_t)am);
  }
  __syncthreads();

  // Pass 2: per-expert column sums of normalized gates (thread e)
  if (tid < 64) {
    const int e = tid;
    float s = 0.f;
    for (int t = 0; t < 64; ++t)
      s += expf(xs[t][(e + t) & 63] - sm_m[t]) * sm_inv[t];
    colsum_ws[(size_t)blockIdx.x * 64 + e] = s;
  }
}

// ---------------- K2: per-expert capacity selection -> compact slotj table ----------------
__global__ __launch_bounds__(256) void k_select(
    const int* __restrict__ expert_ws, const float* __restrict__ uval_ws,
    int* __restrict__ slotj_ws, int* __restrict__ counts_ws,
    float* __restrict__ out)
{
  __shared__ float su[1024];
  __shared__ int   sidx[1024];
  __shared__ int   skept[1024];
  __shared__ int   scnt;

  const int e   = blockIdx.x;
  const int tid = threadIdx.x;
  if (tid == 0) scnt = 0;
  __syncthreads();

  for (int s = tid; s < S_TOK; s += 256) {
    if (expert_ws[s] == e) {
      const int p = atomicAdd(&scnt, 1);
      if (p < 1024) { su[p] = uval_ws[s]; sidx[p] = s; }  // n ~ 256±16; huge headroom
    }
  }
  __syncthreads();
  const int n = min(scnt, 1024);

  if (tid == 0) {
    counts_ws[e] = scnt;
    out[EC_OFF + e] = (float)scnt;   // exp_counts (pre-capacity)
  }

  for (int t = tid; t < n; t += 256) {
    int keep = 1;
    if (n > CAP) {
      const float ut = su[t];
      const int   it = sidx[t];
      int r = 0;
      for (int j = 0; j < n; ++j) {
        const float uj = su[j];
        r += (uj > ut) || (uj == ut && sidx[j] < it);
      }
      keep = (r < CAP);
    }
    skept[t] = keep;
  }
  __syncthreads();

  for (int t = tid; t < n; t += 256) {
    const int it = sidx[t];
    int sj = -1;
    if (skept[t]) {
      int slot = 0;
      for (int j = 0; j < n; ++j) slot += (skept[j] && (sidx[j] < it));
      sj = e * CAP + slot;
    }
    slotj_ws[it] = sj;
  }
}

// ---------------- K3: sparse scatter + l_aux (after memset in stream order) ----------------
__global__ __launch_bounds__(256) void k_scatter_final(
    const int* __restrict__ slotj_ws, const float* __restrict__ alpha_ws,
    const float* __restrict__ colsum_ws, const int* __restrict__ counts_ws,
    float* __restrict__ out)
{
  const int s = blockIdx.x * 256 + threadIdx.x;   // 64 blocks x 256 = 16384 tokens
  const int tj = slotj_ws[s];
  if (tj >= 0) {
    const size_t base = CW_OFF + (size_t)s * (NEXP * CAP) + (size_t)tj;
    out[base]       = alpha_ws[s];   // combine_weights
    out[base + SEC] = 1.0f;          // dispatch_mask
  }

  if (blockIdx.x == 0 && threadIdx.x < 64) {
    const int e = threadIdx.x;
    float cs = 0.f;
    for (int b = 0; b < 256; ++b) cs += colsum_ws[(size_t)b * 64 + e];  // fixed order
    const float me = cs / (float)S_TOK;
    const float ce = (float)counts_ws[e] / (float)S_TOK;
    float v = me * ce;
#pragma unroll
    for (int off = 32; off > 0; off >>= 1) v += __shfl_down(v, off, 64);
    if (e == 0) out[0] = v * (float)NEXP;
  }
}

// ---------------- launch ----------------
extern "C" void kernel_launch(void* const* d_in, const int* in_sizes, int n_in,
                              void* d_out, int out_size, void* d_ws, size_t ws_size,
                              hipStream_t stream)
{
  const float* x  = (const float*)d_in[0];
  const float* wg = (const float*)d_in[1];
  float* out = (float*)d_out;

  // workspace layout
  char* ws = (char*)d_ws;
  int*   expert_ws = (int*)  (ws + 0);        // S ints
  float* uval_ws   = (float*)(ws + 65536);    // S floats
  float* alpha_ws  = (float*)(ws + 131072);   // S floats
  float* colsum_ws = (float*)(ws + 196608);   // 256*64 floats
  int*   counts_ws = (int*)  (ws + 262144);   // 64 ints
  int*   slotj_ws  = (int*)  (ws + 262400);   // S ints

  // Bulk zero via ROCclr fillBufferAligned (proven 6.4 TB/s). Covers
  // [0, 1+2*SEC): l_aux + combine_weights + dispatch_mask. alpha/ec regions
  // are fully overwritten by k_gate / k_select every call.
  hipMemsetAsync(out, 0, (1 + 2 * SEC) * sizeof(float), stream);

  k_gate         <<<256,         256, 0, stream>>>(x, wg, out, expert_ws, uval_ws,
                                                   alpha_ws, colsum_ws);
  k_select       <<<NEXP,        256, 0, stream>>>(expert_ws, uval_ws, slotj_ws,
                                                   counts_ws, out);
  k_scatter_final<<<S_TOK / 256, 256, 0, stream>>>(slotj_ws, alpha_ws, colsum_ws,
                                                   counts_ws, out);
}